// Round 8
// baseline (18535.043 us; speedup 1.0000x reference)
//
#include <hip/hip_runtime.h>
#include <hip/hip_bf16.h>

// LSTMReg on MI355X — round 8: TWO INDEPENDENT BLOCKS PER CU.
// r1-r7 invariant: ~1.1-1.4us per layer-step regardless of structure ->
// the serial per-iteration skeleton (ds_read h -> MFMA -> gate round-trip ->
// barrier) is latency-bound and nothing on the CU hides it (1 block/CU,
// 2 waves/SIMD, lockstep barrier). This round: NB=2->1 (per-block MFMA/VALU
// cost unchanged — cols were redundant), 512 blocks = 2 blocks/CU = 4
// waves/SIMD in TWO independent barrier domains -> stalls of one block are
// hidden under the other's issue. launch_bounds(512,4) pins VGPR<=128 so
// both blocks co-reside. Everything else = r7 (verified mappings).

typedef short bf16x8 __attribute__((ext_vector_type(8)));
typedef float f32x4  __attribute__((ext_vector_type(4)));

#define MFMA16(A, B, C) __builtin_amdgcn_mfma_f32_16x16x32_bf16(A, B, C, 0, 0, 0)

constexpr int T_LEN = 1024;
constexpr int H     = 64;
constexpr int NB    = 1;            // chains per block
constexpr int NTHR  = 512;          // 8 waves
constexpr int NBLK  = 512;          // 512 chains -> 2 blocks per CU

// x fragment buffer: [blk][t][packet(lq)][32 shorts]; packet = k0h,k1h,k0l,k1l
constexpr int    XT_SHORTS   = 4 * 32;                     // 128 shorts per t
constexpr size_t XBLK_SHORTS = (size_t)T_LEN * XT_SHORTS;  // 256 KiB per block

__device__ __forceinline__ short f2bf(float f) {
  unsigned u = __builtin_bit_cast(unsigned, f);
  unsigned r = (u + 0x7fffu + ((u >> 16) & 1u)) >> 16;  // RNE
  return (short)r;
}
__device__ __forceinline__ float bf2f(short s) {
  unsigned u = ((unsigned)(unsigned short)s) << 16;
  return __builtin_bit_cast(float, u);
}
__device__ __forceinline__ float sigm_f(float x) {
  return __builtin_amdgcn_rcpf(1.0f + __expf(-x));
}
__device__ __forceinline__ float tanh_f(float x) {
  return 1.0f - 2.0f * __builtin_amdgcn_rcpf(1.0f + __expf(2.0f * x));
}

// ---- pre-pass: x [512][1024][64] fp32 -> per-block packet order bf16 hi/lo ----
__global__ __launch_bounds__(256, 4) void xconv(const float* __restrict__ x,
                                                short* __restrict__ xf) {
  const int g  = blockIdx.x * 256 + threadIdx.x;  // one thread per (chain,t,lq)
  const int lq = g & 3;
  const int t  = (g >> 2) & (T_LEN - 1);
  const int chain = g >> 12;                      // 0..511 == block id
  const float* src = x + ((size_t)chain * T_LEN + t) * H + 8 * lq;
  float4 v0 = *reinterpret_cast<const float4*>(src);
  float4 v1 = *reinterpret_cast<const float4*>(src + 4);
  float4 v2 = *reinterpret_cast<const float4*>(src + 32);
  float4 v3 = *reinterpret_cast<const float4*>(src + 36);
  float a[8]  = {v0.x, v0.y, v0.z, v0.w, v1.x, v1.y, v1.z, v1.w};
  float c8[8] = {v2.x, v2.y, v2.z, v2.w, v3.x, v3.y, v3.z, v3.w};
  bf16x8 k0h, k0l, k1h, k1l;
#pragma unroll
  for (int e = 0; e < 8; ++e) {
    short h0 = f2bf(a[e]);
    k0h[e] = h0;
    k0l[e] = f2bf(a[e] - bf2f(h0));
    short h1 = f2bf(c8[e]);
    k1h[e] = h1;
    k1l[e] = f2bf(c8[e] - bf2f(h1));
  }
  short* dst = xf + (size_t)chain * XBLK_SHORTS + (size_t)t * XT_SHORTS + lq * 32;
  *reinterpret_cast<bf16x8*>(dst + 0)  = k0h;
  *reinterpret_cast<bf16x8*>(dst + 8)  = k1h;
  *reinterpret_cast<bf16x8*>(dst + 16) = k0l;
  *reinterpret_cast<bf16x8*>(dst + 24) = k1l;
}

// 3-pass over ONE k-tile: hi·hi, lo·hi, hi·lo
__device__ __forceinline__ f32x4 mfma3(bf16x8 wh, bf16x8 wl, bf16x8 kh,
                                       bf16x8 kl, f32x4 acc) {
  acc = MFMA16(wh, kh, acc);
  acc = MFMA16(wl, kh, acc);
  acc = MFMA16(wh, kl, acc);
  return acc;
}

__global__ __launch_bounds__(NTHR, 4) void lstm_fused(
    const short* __restrict__ xf,
    const float* __restrict__ w_ih0, const float* __restrict__ w_hh0,
    const float* __restrict__ b_ih0, const float* __restrict__ b_hh0,
    const float* __restrict__ w_ih1, const float* __restrict__ w_hh1,
    const float* __restrict__ b_ih1, const float* __restrict__ b_hh1,
    const float* __restrict__ fc_w, const float* __restrict__ fc_b,
    float* __restrict__ out) {
  const int tid   = threadIdx.x;
  const int wv    = tid >> 6;
  const int group = wv >> 2;   // 0 = layer0 MFMA waves, 1 = layer1 (+gate duty)
  const int sw    = wv & 3;
  const int l     = tid & 63;
  const int b     = l & 15;    // MFMA col; real chain is col 0
  const int lq    = l >> 4;
  const int blk   = blockIdx.x;  // == chain id

  // h buffers: [buf][part hi/lo][kts][544 shorts]; slot map verified r4-r7.
  __shared__ __align__(16) short h0buf[2][2][2][544];
  __shared__ __align__(16) short h1buf[2][2][2][544];
  __shared__ __align__(16) float bias_s[2][256];
  __shared__ __align__(16) float zbuf[2][4][64];  // [L][gate][h] (1 chain)
  __shared__ float fcw_s[H];
  __shared__ float hfin[H];

  for (int i = tid; i < 2 * 2 * 2 * 544; i += NTHR) {
    ((short*)h0buf)[i] = 0;
    ((short*)h1buf)[i] = 0;
  }
  if (tid < 256)      bias_s[0][tid] = b_ih0[tid] + b_hh0[tid];
  else                bias_s[1][tid - 256] = b_ih1[tid - 256] + b_hh1[tid - 256];
  if (tid < H) fcw_s[tid] = fc_w[tid];

  // ---- this wave's layer weights -> register frags (hi/lo) ----
  const float* wih = group ? w_ih1 : w_ih0;
  const float* whh = group ? w_hh1 : w_hh0;
  bf16x8 whi[4][4], wlo[4][4];
#pragma unroll
  for (int g = 0; g < 4; ++g) {
#pragma unroll
    for (int kt = 0; kt < 4; ++kt) {
      const int row = 64 * g + 16 * sw + b;
      const int k0  = 32 * kt + 8 * lq;
      const float* src = (k0 < 64) ? &wih[row * 64 + k0] : &whh[row * 64 + (k0 - 64)];
      float4 v0 = *reinterpret_cast<const float4*>(src);
      float4 v1 = *reinterpret_cast<const float4*>(src + 4);
      float vv[8] = {v0.x, v0.y, v0.z, v0.w, v1.x, v1.y, v1.z, v1.w};
      bf16x8 hi8, lo8;
#pragma unroll
      for (int e = 0; e < 8; ++e) {
        short hh = f2bf(vv[e]);
        hi8[e] = hh;
        lo8[e] = f2bf(vv[e] - bf2f(hh));
      }
      whi[g][kt] = hi8;
      wlo[g][kt] = lo8;
    }
  }

  __syncthreads();  // bias_s / h-buf zeros visible

  // ---- G0 prologue: accx = bias + W_ih0·x[0]; xc = x[1] ----
  const short* xfl = xf + (size_t)blk * XBLK_SHORTS + (size_t)lq * 32;
  f32x4 accx[4];
  bf16x8 xc0h, xc1h, xc0l, xc1l, xn0h, xn1h, xn0l, xn1l;
  if (group == 0) {
    bf16x8 a0h = *reinterpret_cast<const bf16x8*>(xfl + 0);
    bf16x8 a1h = *reinterpret_cast<const bf16x8*>(xfl + 8);
    bf16x8 a0l = *reinterpret_cast<const bf16x8*>(xfl + 16);
    bf16x8 a1l = *reinterpret_cast<const bf16x8*>(xfl + 24);
#pragma unroll
    for (int g = 0; g < 4; ++g) {
      f32x4 acc = *reinterpret_cast<const f32x4*>(&bias_s[0][64 * g + 16 * sw + 4 * lq]);
      acc = mfma3(whi[g][0], wlo[g][0], a0h, a0l, acc);
      acc = mfma3(whi[g][1], wlo[g][1], a1h, a1l, acc);
      accx[g] = acc;
    }
    const short* p = xfl + XT_SHORTS;
    xc0h = *reinterpret_cast<const bf16x8*>(p + 0);
    xc1h = *reinterpret_cast<const bf16x8*>(p + 8);
    xc0l = *reinterpret_cast<const bf16x8*>(p + 16);
    xc1l = *reinterpret_cast<const bf16x8*>(p + 24);
  }

  // reader offset: all lanes read chain-0 slots (broadcast within 16-lane cols)
  const int rslot = (l >> 4) * 136;
  // gate task (group-1 threads): tasks 0..127 = (L, h)
  const int task = tid - 256;
  const int gL = (task >> 6) & 1, gh = task & 63;
  const bool gvalid = (task < 128);
  // h-frag write slot (verified map, chain 0):
  const int gslot = (gh >> 5) * 544 + ((gh >> 3) & 3) * 136 + (gh & 7);
  float gcstate = 0.0f;
  const f32x4 zf4 = {0.f, 0.f, 0.f, 0.f};

  for (int t = 0; t <= T_LEN; ++t) {
    const int cur = t & 1, nxt = cur ^ 1;

    // h0[t-1] frags: L0 recurrent side, L1 input side
    const short* p0 = &h0buf[cur][0][0][0] + rslot;
    bf16x8 r0h = *reinterpret_cast<const bf16x8*>(p0);
    bf16x8 r1h = *reinterpret_cast<const bf16x8*>(p0 + 544);
    bf16x8 r0l = *reinterpret_cast<const bf16x8*>(p0 + 1088);
    bf16x8 r1l = *reinterpret_cast<const bf16x8*>(p0 + 1632);

    if (group == 0) {
      if (t + 2 < T_LEN) {  // issue x[t+2] load early (consumed next iter)
        const short* p = xfl + (size_t)(t + 2) * XT_SHORTS;
        xn0h = *reinterpret_cast<const bf16x8*>(p + 0);
        xn1h = *reinterpret_cast<const bf16x8*>(p + 8);
        xn0l = *reinterpret_cast<const bf16x8*>(p + 16);
        xn1l = *reinterpret_cast<const bf16x8*>(p + 24);
      }
      if (t < T_LEN) {
        f32x4 aR0[4], aR1[4];
#pragma unroll
        for (int g = 0; g < 4; ++g) {
          aR0[g] = mfma3(whi[g][2], wlo[g][2], r0h, r0l, zf4);
          aR1[g] = mfma3(whi[g][3], wlo[g][3], r1h, r1l, zf4);
        }
        if (b == 0) {
#pragma unroll
          for (int g = 0; g < 4; ++g) {
            f32x4 z = (accx[g] + aR0[g]) + aR1[g];
            *reinterpret_cast<f32x4*>(&zbuf[0][g][16 * sw + 4 * lq]) = z;
          }
        } else {
#pragma unroll
          for (int g = 0; g < 4; ++g) aR0[g] = (accx[g] + aR0[g]) + aR1[g];
        }
      }
    } else {
      // L1: input side on h0[t-1], recurrent side on h1[t-2]
      const short* p1 = &h1buf[cur][0][0][0] + rslot;
      bf16x8 s0h = *reinterpret_cast<const bf16x8*>(p1);
      bf16x8 s1h = *reinterpret_cast<const bf16x8*>(p1 + 544);
      bf16x8 s0l = *reinterpret_cast<const bf16x8*>(p1 + 1088);
      bf16x8 s1l = *reinterpret_cast<const bf16x8*>(p1 + 1632);
      f32x4 aI0[4], aI1[4], aR0[4], aR1[4];
#pragma unroll
      for (int g = 0; g < 4; ++g) {
        f32x4 bi = *reinterpret_cast<const f32x4*>(&bias_s[1][64 * g + 16 * sw + 4 * lq]);
        aI0[g] = mfma3(whi[g][0], wlo[g][0], r0h, r0l, bi);
        aI1[g] = mfma3(whi[g][1], wlo[g][1], r1h, r1l, zf4);
        aR0[g] = mfma3(whi[g][2], wlo[g][2], s0h, s0l, zf4);
        aR1[g] = mfma3(whi[g][3], wlo[g][3], s1h, s1l, zf4);
      }
      if (b == 0) {
#pragma unroll
        for (int g = 0; g < 4; ++g) {
          f32x4 z = (aI0[g] + aI1[g]) + (aR0[g] + aR1[g]);
          *reinterpret_cast<f32x4*>(&zbuf[1][g][16 * sw + 4 * lq]) = z;
        }
      }
    }

    __syncthreads();  // z ready

    if (group == 0) {
      // precompute next step's input side (overlaps gate phase on the SIMD)
      if (t + 1 < T_LEN) {
#pragma unroll
        for (int g = 0; g < 4; ++g) {
          f32x4 acc = *reinterpret_cast<const f32x4*>(&bias_s[0][64 * g + 16 * sw + 4 * lq]);
          acc = mfma3(whi[g][0], wlo[g][0], xc0h, xc0l, acc);
          acc = mfma3(whi[g][1], wlo[g][1], xc1h, xc1l, acc);
          accx[g] = acc;
        }
      }
    } else if (gvalid) {
      // gate phase: one (L,h) task per lane, torch order i,f,g,o
      const bool gact = (gL == 0) ? (t < T_LEN) : (t >= 1);
      if (gact) {
        float zi = zbuf[gL][0][gh];
        float zf = zbuf[gL][1][gh];
        float zg = zbuf[gL][2][gh];
        float zo = zbuf[gL][3][gh];
        float ig = sigm_f(zi), fg = sigm_f(zf);
        float gg = tanh_f(zg), og = sigm_f(zo);
        gcstate = fg * gcstate + ig * gg;
        float hv = og * tanh_f(gcstate);
        if (gL == 1 && t == T_LEN) {
          hfin[gh] = hv;
        } else {
          short hh = f2bf(hv);
          short ll = f2bf(hv - bf2f(hh));
          short* base = gL ? &h1buf[nxt][0][0][0] : &h0buf[nxt][0][0][0];
          base[gslot]        = hh;
          base[1088 + gslot] = ll;
        }
      }
    }

    __syncthreads();  // h[nxt] ready
    if (group == 0) { xc0h = xn0h; xc1h = xn1h; xc0l = xn0l; xc1l = xn1l; }
  }

  // ---- FC epilogue: out[blk] = fc_w . h2[T-1] + fc_b ----
  if (tid == 0) {
    float acc = fc_b[0];
#pragma unroll
    for (int h = 0; h < H; ++h) acc += fcw_s[h] * hfin[h];
    out[blk] = acc;
  }
}

extern "C" void kernel_launch(void* const* d_in, const int* in_sizes, int n_in,
                              void* d_out, int out_size, void* d_ws, size_t ws_size,
                              hipStream_t stream) {
  const float* x     = (const float*)d_in[0];
  const float* w_ih0 = (const float*)d_in[1];
  const float* w_hh0 = (const float*)d_in[2];
  const float* b_ih0 = (const float*)d_in[3];
  const float* b_hh0 = (const float*)d_in[4];
  const float* w_ih1 = (const float*)d_in[5];
  const float* w_hh1 = (const float*)d_in[6];
  const float* b_ih1 = (const float*)d_in[7];
  const float* b_hh1 = (const float*)d_in[8];
  const float* fc_w  = (const float*)d_in[9];
  const float* fc_b  = (const float*)d_in[10];
  float* out = (float*)d_out;

  short* xfrag = (short*)d_ws;  // 128 MiB workspace

  xconv<<<dim3(8192), dim3(256), 0, stream>>>(x, xfrag);
  lstm_fused<<<dim3(NBLK), dim3(NTHR), 0, stream>>>(
      xfrag, w_ih0, w_hh0, b_ih0, b_hh0, w_ih1, w_hh1, b_ih1, b_hh1,
      fc_w, fc_b, out);
}

// Round 9
// 1142.308 us; speedup vs baseline: 16.2260x; 16.2260x over previous
//
#include <hip/hip_runtime.h>
#include <hip/hip_bf16.h>

// LSTMReg on MI355X — round 9: FILL THE MFMA COLUMNS (kill the redundancy).
// Correct issue model (r8 analysis): 16x16x32 bf16 MFMA ~19.4 cyc per SIMD;
// r2-r7 were MFMA-issue-bound with 16x column waste + 3-pass.
// New: 64 blocks x 1024 thr (16 waves = 4/SIMD). 8 chains/block; MFMA col =
// (chain, hi/lo part) -> 2-pass hi/lo-in-columns, zero wasted columns:
//   pass A=Whi over cols(xhi|xlo) + pass A=Wlo -> z = col(2c)+col(2c+1)
//   = (Whi+Wlo)(xhi+xlo) = full product.
// Per block 256 MFMAs/iter -> 16/wave -> ~1242 cyc/SIMD/iter (vs r7 ~1860).
// Gate phase: 1024 tasks = 1/thread. Regs/wave ~115 <= 128 cap (r8 lesson).

typedef short bf16x8 __attribute__((ext_vector_type(8)));
typedef float f32x4  __attribute__((ext_vector_type(4)));

#define MFMA16(A, B, C) __builtin_amdgcn_mfma_f32_16x16x32_bf16(A, B, C, 0, 0, 0)

constexpr int T_LEN = 1024;
constexpr int H     = 64;
constexpr int NCH   = 8;     // chains per block
constexpr int NTHR  = 1024;  // 16 waves
constexpr int NBLK  = 64;    // 512 chains / 8

// x fragment buffer: [blk][t][kt(2)][lane(64)][8 shorts]
constexpr int    XT_SHORTS   = 2 * 64 * 8;                 // 1024 shorts per t
constexpr size_t XBLK_SHORTS = (size_t)T_LEN * XT_SHORTS;  // 2 MiB per block (x64 = 128 MiB)

__device__ __forceinline__ short f2bf(float f) {
  unsigned u = __builtin_bit_cast(unsigned, f);
  unsigned r = (u + 0x7fffu + ((u >> 16) & 1u)) >> 16;  // RNE
  return (short)r;
}
__device__ __forceinline__ float bf2f(short s) {
  unsigned u = ((unsigned)(unsigned short)s) << 16;
  return __builtin_bit_cast(float, u);
}
__device__ __forceinline__ float sigm_f(float x) {
  return __builtin_amdgcn_rcpf(1.0f + __expf(-x));
}
__device__ __forceinline__ float tanh_f(float x) {
  return 1.0f - 2.0f * __builtin_amdgcn_rcpf(1.0f + __expf(2.0f * x));
}

// ---- pre-pass: pack x into B-fragment packets, col parity = hi/lo part ----
// lane l -> part p=l&1, chain ch=(l>>1)&7, feat f0=8*(l>>4).
__global__ __launch_bounds__(256, 4) void xconv(const float* __restrict__ x,
                                                short* __restrict__ xf) {
  const int gid = blockIdx.x * 256 + threadIdx.x;
  const int l   = gid & 63;
  const int t   = (gid >> 6) & (T_LEN - 1);
  const int blk = gid >> 16;
  const int part = l & 1, ch = (l >> 1) & 7, f0 = (l >> 4) * 8;
  const float* src = x + ((size_t)(blk * NCH + ch) * T_LEN + t) * H + f0;
  float4 v0 = *reinterpret_cast<const float4*>(src);
  float4 v1 = *reinterpret_cast<const float4*>(src + 4);
  float4 v2 = *reinterpret_cast<const float4*>(src + 32);
  float4 v3 = *reinterpret_cast<const float4*>(src + 36);
  float a[8]  = {v0.x, v0.y, v0.z, v0.w, v1.x, v1.y, v1.z, v1.w};
  float c8[8] = {v2.x, v2.y, v2.z, v2.w, v3.x, v3.y, v3.z, v3.w};
  bf16x8 p0, p1;
#pragma unroll
  for (int e = 0; e < 8; ++e) {
    short h0 = f2bf(a[e]);
    short h1 = f2bf(c8[e]);
    if (part == 0) { p0[e] = h0; p1[e] = h1; }
    else { p0[e] = f2bf(a[e] - bf2f(h0)); p1[e] = f2bf(c8[e] - bf2f(h1)); }
  }
  short* dst = xf + (size_t)blk * XBLK_SHORTS + (size_t)t * XT_SHORTS + l * 8;
  *reinterpret_cast<bf16x8*>(dst)       = p0;  // kt0 (feats 0-31)
  *reinterpret_cast<bf16x8*>(dst + 512) = p1;  // kt1 (feats 32-63)
}

__global__ __launch_bounds__(NTHR) void lstm_fused(
    const short* __restrict__ xf,
    const float* __restrict__ w_ih0, const float* __restrict__ w_hh0,
    const float* __restrict__ b_ih0, const float* __restrict__ b_hh0,
    const float* __restrict__ w_ih1, const float* __restrict__ w_hh1,
    const float* __restrict__ b_ih1, const float* __restrict__ b_hh1,
    const float* __restrict__ fc_w, const float* __restrict__ fc_b,
    float* __restrict__ out) {
  const int tid = threadIdx.x;
  const int wv  = tid >> 6;
  const int L   = wv >> 3;   // 0: layer0 waves, 1: layer1 waves
  const int w8  = wv & 7;    // row-block: rows [32*w8, 32*w8+32)
  const int l   = tid & 63;
  const int col = l & 15;    // MFMA column = 2*chain + part
  const int lq  = l >> 4;
  const int blk = blockIdx.x;

  // h buffers, fragment-linear + XOR swizzle: [hLayer][buf][half][520 shorts]
  // slot(p,ch,q) = (q<<4) | (((ch<<1)|p) ^ (q<<1)); lane reads its own slot.
  __shared__ __align__(16) short hb[2][2][2][520];   // 8320 B (520 = 65 slots pad)
  __shared__ __align__(16) float zp[2][16][260];     // [L][col][row(+pad)] 33280 B
  __shared__ float bias_s[2][256];
  __shared__ float fcw_s[H];
  __shared__ float hfin[NCH][H];

  for (int i = tid; i < 2 * 2 * 2 * 520; i += NTHR) ((short*)hb)[i] = 0;
  if (tid < 256)       bias_s[0][tid] = b_ih0[tid] + b_hh0[tid];
  else if (tid < 512)  bias_s[1][tid - 256] = b_ih1[tid - 256] + b_hh1[tid - 256];
  if (tid < H) fcw_s[tid] = fc_w[tid];

  // ---- weights: wave covers rows 32*w8 + 16*rt + col, kt: k0 = 32kt+8lq ----
  const float* wih = L ? w_ih1 : w_ih0;
  const float* whh = L ? w_hh1 : w_hh0;
  bf16x8 whi[2][4], wlo[2][4];  // 64 VGPR
#pragma unroll
  for (int rt = 0; rt < 2; ++rt) {
#pragma unroll
    for (int kt = 0; kt < 4; ++kt) {
      const int row = 32 * w8 + 16 * rt + col;
      const int k0  = 32 * kt + 8 * lq;
      const float* src = (k0 < 64) ? &wih[row * 64 + k0] : &whh[row * 64 + (k0 - 64)];
      float4 v0 = *reinterpret_cast<const float4*>(src);
      float4 v1 = *reinterpret_cast<const float4*>(src + 4);
      float vv[8] = {v0.x, v0.y, v0.z, v0.w, v1.x, v1.y, v1.z, v1.w};
      bf16x8 hi8, lo8;
#pragma unroll
      for (int e = 0; e < 8; ++e) {
        short hh = f2bf(vv[e]);
        hi8[e] = hh;
        lo8[e] = f2bf(vv[e] - bf2f(hh));
      }
      whi[rt][kt] = hi8;
      wlo[rt][kt] = lo8;
    }
  }

  __syncthreads();

  // reader LDS offset (shorts): swizzled slot * 8
  const int rdoff = ((l & 48) | ((l & 15) ^ ((l >> 4) << 1))) * 8;

  // gate task: (L, ch, h) = (wave layer, wave&7, lane)
  const int gch = wv & 7, gh = l;
  const int ghalf = gh >> 5, glq = (gh >> 3) & 3, ge = gh & 7;
  const int slot0 = (glq << 4) | (((gch << 1) | 0) ^ (glq << 1));
  const int gw0 = ghalf * 520 + slot0 * 8 + ge;        // hi (p=0)
  const int gw1 = ghalf * 520 + (slot0 | 1) * 8 + ge;  // lo (p=1)
  float cst = 0.0f;

  // x prefetch (L0 waves)
  const short* xfl = xf + (size_t)blk * XBLK_SHORTS + l * 8;
  bf16x8 xb0, xb1, xb0n, xb1n;
  if (L == 0) {
    xb0 = *reinterpret_cast<const bf16x8*>(xfl);
    xb1 = *reinterpret_cast<const bf16x8*>(xfl + 512);
  }

  const f32x4 zf4 = {0.f, 0.f, 0.f, 0.f};

#define KT4(B0_, B1_, B2_, B3_)                             \
  a0 = MFMA16(whi[0][0], B0_, a0); a1 = MFMA16(whi[1][0], B0_, a1); \
  a0 = MFMA16(wlo[0][0], B0_, a0); a1 = MFMA16(wlo[1][0], B0_, a1); \
  a0 = MFMA16(whi[0][1], B1_, a0); a1 = MFMA16(whi[1][1], B1_, a1); \
  a0 = MFMA16(wlo[0][1], B1_, a0); a1 = MFMA16(wlo[1][1], B1_, a1); \
  a0 = MFMA16(whi[0][2], B2_, a0); a1 = MFMA16(whi[1][2], B2_, a1); \
  a0 = MFMA16(wlo[0][2], B2_, a0); a1 = MFMA16(wlo[1][2], B2_, a1); \
  a0 = MFMA16(whi[0][3], B3_, a0); a1 = MFMA16(whi[1][3], B3_, a1); \
  a0 = MFMA16(wlo[0][3], B3_, a0); a1 = MFMA16(wlo[1][3], B3_, a1);

  for (int t = 0; t <= T_LEN; ++t) {
    const int cur = t & 1, nxt = cur ^ 1;

    if (L == 0) {
      if (t + 1 < T_LEN) {  // prefetch next x packets (consumed next iter)
        const short* p = xfl + (size_t)(t + 1) * XT_SHORTS;
        xb0n = *reinterpret_cast<const bf16x8*>(p);
        xb1n = *reinterpret_cast<const bf16x8*>(p + 512);
      }
      if (t < T_LEN) {
        const short* h0c = &hb[0][cur][0][0];
        bf16x8 B2 = *reinterpret_cast<const bf16x8*>(h0c + rdoff);        // h0 feats 0-31
        bf16x8 B3 = *reinterpret_cast<const bf16x8*>(h0c + 520 + rdoff);  // h0 feats 32-63
        f32x4 a0 = zf4, a1 = zf4;
        KT4(xb0, xb1, B2, B3)
        *reinterpret_cast<f32x4*>(&zp[0][col][32 * w8 + 4 * lq])      = a0;
        *reinterpret_cast<f32x4*>(&zp[0][col][32 * w8 + 16 + 4 * lq]) = a1;
      }
    } else {
      if (t >= 1) {
        const short* h0c = &hb[0][cur][0][0];
        const short* h1c = &hb[1][cur][0][0];
        bf16x8 B0 = *reinterpret_cast<const bf16x8*>(h0c + rdoff);
        bf16x8 B1 = *reinterpret_cast<const bf16x8*>(h0c + 520 + rdoff);
        bf16x8 B2 = *reinterpret_cast<const bf16x8*>(h1c + rdoff);
        bf16x8 B3 = *reinterpret_cast<const bf16x8*>(h1c + 520 + rdoff);
        f32x4 a0 = zf4, a1 = zf4;
        KT4(B0, B1, B2, B3)
        *reinterpret_cast<f32x4*>(&zp[1][col][32 * w8 + 4 * lq])      = a0;
        *reinterpret_cast<f32x4*>(&zp[1][col][32 * w8 + 16 + 4 * lq]) = a1;
      }
    }

    __syncthreads();  // z ready

    const bool act = (L == 0) ? (t < T_LEN) : (t >= 1);
    if (act) {
      // z = colEven + colOdd + bias  (torch gate order i,f,g,o by row blocks)
      const float* ze = &zp[L][2 * gch][0];
      const float* zo_ = &zp[L][2 * gch + 1][0];
      float z0 = ze[gh]       + zo_[gh]       + bias_s[L][gh];
      float z1 = ze[64 + gh]  + zo_[64 + gh]  + bias_s[L][64 + gh];
      float z2 = ze[128 + gh] + zo_[128 + gh] + bias_s[L][128 + gh];
      float z3 = ze[192 + gh] + zo_[192 + gh] + bias_s[L][192 + gh];
      float ig = sigm_f(z0), fg = sigm_f(z1);
      float gg = tanh_f(z2), og = sigm_f(z3);
      cst = fg * cst + ig * gg;
      float hv = og * tanh_f(cst);
      if (L == 1 && t == T_LEN) {
        hfin[gch][gh] = hv;
      } else {
        short hi = f2bf(hv);
        short lo = f2bf(hv - bf2f(hi));
        short* base = &hb[L][nxt][0][0];
        base[gw0] = hi;
        base[gw1] = lo;
      }
    }

    __syncthreads();  // h[nxt] ready
    if (L == 0) { xb0 = xb0n; xb1 = xb1n; }
  }
#undef KT4

  // ---- FC epilogue ----
  if (tid < NCH) {
    float acc = fc_b[0];
#pragma unroll
    for (int h = 0; h < H; ++h) acc += fcw_s[h] * hfin[tid][h];
    out[blk * NCH + tid] = acc;
  }
}

extern "C" void kernel_launch(void* const* d_in, const int* in_sizes, int n_in,
                              void* d_out, int out_size, void* d_ws, size_t ws_size,
                              hipStream_t stream) {
  const float* x     = (const float*)d_in[0];
  const float* w_ih0 = (const float*)d_in[1];
  const float* w_hh0 = (const float*)d_in[2];
  const float* b_ih0 = (const float*)d_in[3];
  const float* b_hh0 = (const float*)d_in[4];
  const float* w_ih1 = (const float*)d_in[5];
  const float* w_hh1 = (const float*)d_in[6];
  const float* b_ih1 = (const float*)d_in[7];
  const float* b_hh1 = (const float*)d_in[8];
  const float* fc_w  = (const float*)d_in[9];
  const float* fc_b  = (const float*)d_in[10];
  float* out = (float*)d_out;

  short* xfrag = (short*)d_ws;  // 128 MiB exactly

  // 64 blk * 1024 t * 64 lanes = 4,194,304 threads / 256
  xconv<<<dim3(16384), dim3(256), 0, stream>>>(x, xfrag);
  lstm_fused<<<dim3(NBLK), dim3(NTHR), 0, stream>>>(
      xfrag, w_ih0, w_hh0, b_ih0, b_hh0, w_ih1, w_hh1, b_ih1, b_hh1,
      fc_w, fc_b, out);
}

// Round 10
// 1064.561 us; speedup vs baseline: 17.4110x; 1.0730x over previous
//
#include <hip/hip_runtime.h>
#include <hip/hip_bf16.h>

// LSTMReg on MI355X — round 10: r9 + L0 input-side MFMA moved into the gate
// phase. r9 analysis: iter = 2440 cyc, of which ~1242 is MFMA issue (48+16
// split) and ~1200 is the serialized gate phase + barriers where the MFMA
// pipe idles. L0's x-side projection (k-tiles 0,1) depends only on
// register-prefetched x[t+1] -> compute it in phase 2 interleaved with gate
// VALU (separate pipes, same wave). Phase-1 MFMA issue/SIMD: 64 -> 48.
// Accumulation order per value unchanged -> bit-identical (r9 absmax 0.0).

typedef short bf16x8 __attribute__((ext_vector_type(8)));
typedef float f32x4  __attribute__((ext_vector_type(4)));

#define MFMA16(A, B, C) __builtin_amdgcn_mfma_f32_16x16x32_bf16(A, B, C, 0, 0, 0)

constexpr int T_LEN = 1024;
constexpr int H     = 64;
constexpr int NCH   = 8;     // chains per block
constexpr int NTHR  = 1024;  // 16 waves
constexpr int NBLK  = 64;    // 512 chains / 8

// x fragment buffer: [blk][t][kt(2)][lane(64)][8 shorts]
constexpr int    XT_SHORTS   = 2 * 64 * 8;                 // 1024 shorts per t
constexpr size_t XBLK_SHORTS = (size_t)T_LEN * XT_SHORTS;  // 2 MiB per block

__device__ __forceinline__ short f2bf(float f) {
  unsigned u = __builtin_bit_cast(unsigned, f);
  unsigned r = (u + 0x7fffu + ((u >> 16) & 1u)) >> 16;  // RNE
  return (short)r;
}
__device__ __forceinline__ float bf2f(short s) {
  unsigned u = ((unsigned)(unsigned short)s) << 16;
  return __builtin_bit_cast(float, u);
}
__device__ __forceinline__ float sigm_f(float x) {
  return __builtin_amdgcn_rcpf(1.0f + __expf(-x));
}
__device__ __forceinline__ float tanh_f(float x) {
  return 1.0f - 2.0f * __builtin_amdgcn_rcpf(1.0f + __expf(2.0f * x));
}

// ---- pre-pass: pack x into B-fragment packets, col parity = hi/lo part ----
__global__ __launch_bounds__(256, 4) void xconv(const float* __restrict__ x,
                                                short* __restrict__ xf) {
  const int gid = blockIdx.x * 256 + threadIdx.x;
  const int l   = gid & 63;
  const int t   = (gid >> 6) & (T_LEN - 1);
  const int blk = gid >> 16;
  const int part = l & 1, ch = (l >> 1) & 7, f0 = (l >> 4) * 8;
  const float* src = x + ((size_t)(blk * NCH + ch) * T_LEN + t) * H + f0;
  float4 v0 = *reinterpret_cast<const float4*>(src);
  float4 v1 = *reinterpret_cast<const float4*>(src + 4);
  float4 v2 = *reinterpret_cast<const float4*>(src + 32);
  float4 v3 = *reinterpret_cast<const float4*>(src + 36);
  float a[8]  = {v0.x, v0.y, v0.z, v0.w, v1.x, v1.y, v1.z, v1.w};
  float c8[8] = {v2.x, v2.y, v2.z, v2.w, v3.x, v3.y, v3.z, v3.w};
  bf16x8 p0, p1;
#pragma unroll
  for (int e = 0; e < 8; ++e) {
    short h0 = f2bf(a[e]);
    short h1 = f2bf(c8[e]);
    if (part == 0) { p0[e] = h0; p1[e] = h1; }
    else { p0[e] = f2bf(a[e] - bf2f(h0)); p1[e] = f2bf(c8[e] - bf2f(h1)); }
  }
  short* dst = xf + (size_t)blk * XBLK_SHORTS + (size_t)t * XT_SHORTS + l * 8;
  *reinterpret_cast<bf16x8*>(dst)       = p0;  // kt0 (feats 0-31)
  *reinterpret_cast<bf16x8*>(dst + 512) = p1;  // kt1 (feats 32-63)
}

__global__ __launch_bounds__(NTHR) void lstm_fused(
    const short* __restrict__ xf,
    const float* __restrict__ w_ih0, const float* __restrict__ w_hh0,
    const float* __restrict__ b_ih0, const float* __restrict__ b_hh0,
    const float* __restrict__ w_ih1, const float* __restrict__ w_hh1,
    const float* __restrict__ b_ih1, const float* __restrict__ b_hh1,
    const float* __restrict__ fc_w, const float* __restrict__ fc_b,
    float* __restrict__ out) {
  const int tid = threadIdx.x;
  const int wv  = tid >> 6;
  const int L   = wv >> 3;   // 0: layer0 waves, 1: layer1 waves
  const int w8  = wv & 7;    // row-block: rows [32*w8, 32*w8+32)
  const int l   = tid & 63;
  const int col = l & 15;    // MFMA column = 2*chain + part
  const int lq  = l >> 4;
  const int blk = blockIdx.x;

  // h buffers, fragment-linear + XOR swizzle (verified r9)
  __shared__ __align__(16) short hb[2][2][2][520];   // 8320 B
  __shared__ __align__(16) float zp[2][16][260];     // [L][col][row(+pad)]
  __shared__ float bias_s[2][256];
  __shared__ float fcw_s[H];
  __shared__ float hfin[NCH][H];

  for (int i = tid; i < 2 * 2 * 2 * 520; i += NTHR) ((short*)hb)[i] = 0;
  if (tid < 256)       bias_s[0][tid] = b_ih0[tid] + b_hh0[tid];
  else if (tid < 512)  bias_s[1][tid - 256] = b_ih1[tid - 256] + b_hh1[tid - 256];
  if (tid < H) fcw_s[tid] = fc_w[tid];

  // ---- weights: wave covers rows 32*w8 + 16*rt + col, kt: k0 = 32kt+8lq ----
  const float* wih = L ? w_ih1 : w_ih0;
  const float* whh = L ? w_hh1 : w_hh0;
  bf16x8 whi[2][4], wlo[2][4];  // 64 VGPR
#pragma unroll
  for (int rt = 0; rt < 2; ++rt) {
#pragma unroll
    for (int kt = 0; kt < 4; ++kt) {
      const int row = 32 * w8 + 16 * rt + col;
      const int k0  = 32 * kt + 8 * lq;
      const float* src = (k0 < 64) ? &wih[row * 64 + k0] : &whh[row * 64 + (k0 - 64)];
      float4 v0 = *reinterpret_cast<const float4*>(src);
      float4 v1 = *reinterpret_cast<const float4*>(src + 4);
      float vv[8] = {v0.x, v0.y, v0.z, v0.w, v1.x, v1.y, v1.z, v1.w};
      bf16x8 hi8, lo8;
#pragma unroll
      for (int e = 0; e < 8; ++e) {
        short hh = f2bf(vv[e]);
        hi8[e] = hh;
        lo8[e] = f2bf(vv[e] - bf2f(hh));
      }
      whi[rt][kt] = hi8;
      wlo[rt][kt] = lo8;
    }
  }

  // x-side macro (k-tiles 0,1) into ax; recurrent macro (k-tiles 2,3) into a.
#define KTX(B0_, B1_)                                               \
  ax0 = MFMA16(whi[0][0], B0_, ax0); ax1 = MFMA16(whi[1][0], B0_, ax1); \
  ax0 = MFMA16(wlo[0][0], B0_, ax0); ax1 = MFMA16(wlo[1][0], B0_, ax1); \
  ax0 = MFMA16(whi[0][1], B1_, ax0); ax1 = MFMA16(whi[1][1], B1_, ax1); \
  ax0 = MFMA16(wlo[0][1], B1_, ax0); ax1 = MFMA16(wlo[1][1], B1_, ax1);
#define KT2(B2_, B3_)                                               \
  a0 = MFMA16(whi[0][2], B2_, a0); a1 = MFMA16(whi[1][2], B2_, a1); \
  a0 = MFMA16(wlo[0][2], B2_, a0); a1 = MFMA16(wlo[1][2], B2_, a1); \
  a0 = MFMA16(whi[0][3], B3_, a0); a1 = MFMA16(whi[1][3], B3_, a1); \
  a0 = MFMA16(wlo[0][3], B3_, a0); a1 = MFMA16(wlo[1][3], B3_, a1);
#define KT4(B0_, B1_, B2_, B3_)                                     \
  a0 = MFMA16(whi[0][0], B0_, a0); a1 = MFMA16(whi[1][0], B0_, a1); \
  a0 = MFMA16(wlo[0][0], B0_, a0); a1 = MFMA16(wlo[1][0], B0_, a1); \
  a0 = MFMA16(whi[0][1], B1_, a0); a1 = MFMA16(whi[1][1], B1_, a1); \
  a0 = MFMA16(wlo[0][1], B1_, a0); a1 = MFMA16(wlo[1][1], B1_, a1); \
  a0 = MFMA16(whi[0][2], B2_, a0); a1 = MFMA16(whi[1][2], B2_, a1); \
  a0 = MFMA16(wlo[0][2], B2_, a0); a1 = MFMA16(wlo[1][2], B2_, a1); \
  a0 = MFMA16(whi[0][3], B3_, a0); a1 = MFMA16(whi[1][3], B3_, a1); \
  a0 = MFMA16(wlo[0][3], B3_, a0); a1 = MFMA16(wlo[1][3], B3_, a1);

  const f32x4 zf4 = {0.f, 0.f, 0.f, 0.f};

  // ---- L0 prologue: ax = x-side z for step 0 (regs only, pre-barrier) ----
  const short* xfl = xf + (size_t)blk * XBLK_SHORTS + l * 8;
  f32x4 ax0 = zf4, ax1 = zf4;
  bf16x8 xbn0, xbn1;
  if (L == 0) {
    bf16x8 x0 = *reinterpret_cast<const bf16x8*>(xfl);
    bf16x8 x1 = *reinterpret_cast<const bf16x8*>(xfl + 512);
    KTX(x0, x1)
  }

  __syncthreads();  // bias_s / h-buf zeros visible

  // reader LDS offset (shorts): swizzled slot * 8
  const int rdoff = ((l & 48) | ((l & 15) ^ ((l >> 4) << 1))) * 8;
  // gate task: (L, ch, h) = (wave layer, wave&7, lane)
  const int gch = wv & 7, gh = l;
  const int ghalf = gh >> 5, glq = (gh >> 3) & 3, ge = gh & 7;
  const int slot0 = (glq << 4) | (((gch << 1) | 0) ^ (glq << 1));
  const int gw0 = ghalf * 520 + slot0 * 8 + ge;        // hi (p=0)
  const int gw1 = ghalf * 520 + (slot0 | 1) * 8 + ge;  // lo (p=1)
  float cst = 0.0f;

  for (int t = 0; t <= T_LEN; ++t) {
    const int cur = t & 1, nxt = cur ^ 1;

    if (L == 0) {
      if (t + 1 < T_LEN) {  // prefetch x[t+1] packets (consumed in phase 2)
        const short* p = xfl + (size_t)(t + 1) * XT_SHORTS;
        xbn0 = *reinterpret_cast<const bf16x8*>(p);
        xbn1 = *reinterpret_cast<const bf16x8*>(p + 512);
      }
      if (t < T_LEN) {
        const short* h0c = &hb[0][cur][0][0];
        bf16x8 B2 = *reinterpret_cast<const bf16x8*>(h0c + rdoff);
        bf16x8 B3 = *reinterpret_cast<const bf16x8*>(h0c + 520 + rdoff);
        f32x4 a0 = ax0, a1 = ax1;  // x-side precomputed (same acc order as r9)
        KT2(B2, B3)
        *reinterpret_cast<f32x4*>(&zp[0][col][32 * w8 + 4 * lq])      = a0;
        *reinterpret_cast<f32x4*>(&zp[0][col][32 * w8 + 16 + 4 * lq]) = a1;
      }
    } else {
      if (t >= 1) {
        const short* h0c = &hb[0][cur][0][0];
        const short* h1c = &hb[1][cur][0][0];
        bf16x8 B0 = *reinterpret_cast<const bf16x8*>(h0c + rdoff);
        bf16x8 B1 = *reinterpret_cast<const bf16x8*>(h0c + 520 + rdoff);
        bf16x8 B2 = *reinterpret_cast<const bf16x8*>(h1c + rdoff);
        bf16x8 B3 = *reinterpret_cast<const bf16x8*>(h1c + 520 + rdoff);
        f32x4 a0 = zf4, a1 = zf4;
        KT4(B0, B1, B2, B3)
        *reinterpret_cast<f32x4*>(&zp[1][col][32 * w8 + 4 * lq])      = a0;
        *reinterpret_cast<f32x4*>(&zp[1][col][32 * w8 + 16 + 4 * lq]) = a1;
      }
    }

    __syncthreads();  // z ready

    // phase 2: L0 waves interleave next-step x-side MFMA with gate VALU
    if (L == 0 && t + 1 < T_LEN) {
      ax0 = zf4; ax1 = zf4;
      KTX(xbn0, xbn1)
    }

    const bool act = (L == 0) ? (t < T_LEN) : (t >= 1);
    if (act) {
      const float* ze  = &zp[L][2 * gch][0];
      const float* zo_ = &zp[L][2 * gch + 1][0];
      float z0 = ze[gh]       + zo_[gh]       + bias_s[L][gh];
      float z1 = ze[64 + gh]  + zo_[64 + gh]  + bias_s[L][64 + gh];
      float z2 = ze[128 + gh] + zo_[128 + gh] + bias_s[L][128 + gh];
      float z3 = ze[192 + gh] + zo_[192 + gh] + bias_s[L][192 + gh];
      float ig = sigm_f(z0), fg = sigm_f(z1);
      float gg = tanh_f(z2), og = sigm_f(z3);
      cst = fg * cst + ig * gg;
      float hv = og * tanh_f(cst);
      if (L == 1 && t == T_LEN) {
        hfin[gch][gh] = hv;
      } else {
        short hi = f2bf(hv);
        short lo = f2bf(hv - bf2f(hi));
        short* base = &hb[L][nxt][0][0];
        base[gw0] = hi;
        base[gw1] = lo;
      }
    }

    __syncthreads();  // h[nxt] ready
  }
#undef KT4
#undef KT2
#undef KTX

  // ---- FC epilogue ----
  if (tid < NCH) {
    float acc = fc_b[0];
#pragma unroll
    for (int h = 0; h < H; ++h) acc += fcw_s[h] * hfin[tid][h];
    out[blk * NCH + tid] = acc;
  }
}

extern "C" void kernel_launch(void* const* d_in, const int* in_sizes, int n_in,
                              void* d_out, int out_size, void* d_ws, size_t ws_size,
                              hipStream_t stream) {
  const float* x     = (const float*)d_in[0];
  const float* w_ih0 = (const float*)d_in[1];
  const float* w_hh0 = (const float*)d_in[2];
  const float* b_ih0 = (const float*)d_in[3];
  const float* b_hh0 = (const float*)d_in[4];
  const float* w_ih1 = (const float*)d_in[5];
  const float* w_hh1 = (const float*)d_in[6];
  const float* b_ih1 = (const float*)d_in[7];
  const float* b_hh1 = (const float*)d_in[8];
  const float* fc_w  = (const float*)d_in[9];
  const float* fc_b  = (const float*)d_in[10];
  float* out = (float*)d_out;

  short* xfrag = (short*)d_ws;  // 128 MiB exactly

  xconv<<<dim3(16384), dim3(256), 0, stream>>>(x, xfrag);
  lstm_fused<<<dim3(NBLK), dim3(NTHR), 0, stream>>>(
      xfrag, w_ih0, w_hh0, b_ih0, b_hh0, w_ih1, w_hh1, b_ih1, b_hh1,
      fc_w, fc_b, out);
}